// Round 1
// baseline (1150.997 us; speedup 1.0000x reference)
//
#include <hip/hip_runtime.h>

#define BN_EPS 1e-5f

// ---------------------------------------------------------------- block reduce
__device__ __forceinline__ float block_sum(float v) {
  __shared__ float red[9];
  int lane = threadIdx.x & 63;
  int wid  = threadIdx.x >> 6;
  #pragma unroll
  for (int off = 32; off; off >>= 1) v += __shfl_down(v, off, 64);
  __syncthreads();
  if (lane == 0) red[wid] = v;
  __syncthreads();
  if (threadIdx.x == 0) {
    float s = 0.f;
    int nw = (blockDim.x + 63) >> 6;
    for (int i = 0; i < nw; i++) s += red[i];
    red[8] = s;
  }
  __syncthreads();
  return red[8];
}

// ---------------------------------------------------------------- conv stem
// x [32,3,32,32], w [16,3,3,3], out [32,16,32,32], pad=1 stride=1 (SAME)
__global__ void conv_stem(const float* __restrict__ x, const float* __restrict__ w,
                          float* __restrict__ out) {
  int idx = blockIdx.x * blockDim.x + threadIdx.x;
  if (idx >= 32 * 16 * 32 * 32) return;
  int wo = idx & 31, ho = (idx >> 5) & 31, co = (idx >> 10) & 15, b = idx >> 14;
  float acc = 0.f;
  #pragma unroll
  for (int ci = 0; ci < 3; ci++) {
    #pragma unroll
    for (int kh = 0; kh < 3; kh++) {
      int hh = ho + kh - 1;
      #pragma unroll
      for (int kw = 0; kw < 3; kw++) {
        int ww = wo + kw - 1;
        float xv = (hh >= 0 && hh < 32 && ww >= 0 && ww < 32)
                 ? x[((b * 3 + ci) * 32 + hh) * 32 + ww] : 0.f;
        acc += xv * w[((co * 3 + ci) * 3 + kh) * 3 + kw];
      }
    }
  }
  out[idx] = acc;
}

// ---------------------------------------------------------------- adder2d
// out[b,co,ho,wo] = -sum_{ci,kh,kw} |x[b,ci,ho*s+kh-pad, wo*s+kw-pad] - w[co,ci,kh,kw]|
// Out-of-bounds x is 0 (zero-padded patches) and STILL contributes |0-w|.
template<int K>
__global__ void adder2d_k(const float* __restrict__ x, const float* __restrict__ w,
                          float* __restrict__ out,
                          int B, int Cin, int Cout, int H, int W,
                          int Ho, int Wo, int stride, int pad, int total) {
  int idx = blockIdx.x * blockDim.x + threadIdx.x;
  if (idx >= total) return;
  int wo = idx % Wo; int t = idx / Wo;
  int ho = t % Ho; t /= Ho;
  int co = t % Cout; int b = t / Cout;
  const float* wp = w + co * Cin * K * K;
  float acc = 0.f;
  for (int ci = 0; ci < Cin; ci++) {
    const float* xp = x + (b * Cin + ci) * H * W;
    #pragma unroll
    for (int kh = 0; kh < K; kh++) {
      int hh = ho * stride + kh - pad;
      bool hv = (hh >= 0) && (hh < H);
      #pragma unroll
      for (int kw = 0; kw < K; kw++) {
        int ww = wo * stride + kw - pad;
        float xv = (hv && ww >= 0 && ww < W) ? xp[hh * W + ww] : 0.f;
        acc += fabsf(xv - wp[(ci * K + kh) * K + kw]);
      }
    }
  }
  out[idx] = -acc;
}

// ---------------------------------------------------------------- BN stats
// Two-pass per-channel mean / rstd over (B, H*W). stats layout: [mean[C], rstd[C]]
__global__ void bn_stats(const float* __restrict__ x, float* __restrict__ stats,
                         int B, int C, int HW) {
  int c = blockIdx.x;
  float s = 0.f;
  for (int b = 0; b < B; b++) {
    const float* p = x + (b * C + c) * HW;
    for (int i = threadIdx.x; i < HW; i += blockDim.x) s += p[i];
  }
  float tot = block_sum(s);
  float m = tot / (float)(B * HW);
  float v = 0.f;
  for (int b = 0; b < B; b++) {
    const float* p = x + (b * C + c) * HW;
    for (int i = threadIdx.x; i < HW; i += blockDim.x) {
      float d = p[i] - m;
      v += d * d;
    }
  }
  float vt = block_sum(v);
  if (threadIdx.x == 0) {
    stats[c]     = m;
    stats[C + c] = rsqrtf(vt / (float)(B * HW) + BN_EPS);
  }
}

// ---------------------------------------------------------------- BN apply
// MODE 0: bn   MODE 1: bn+relu   MODE 2: bn + residual + relu
template<int MODE>
__global__ void bn_apply(const float* __restrict__ x, const float* __restrict__ stats,
                         const float* __restrict__ res, float* __restrict__ out,
                         int C, int HW, int total) {
  int idx = blockIdx.x * blockDim.x + threadIdx.x;
  if (idx >= total) return;
  int c = (idx / HW) % C;
  float y = (x[idx] - stats[c]) * stats[C + c];
  if (MODE == 1) y = fmaxf(y, 0.f);
  if (MODE == 2) { y += res[idx]; y = fmaxf(y, 0.f); }
  out[idx] = y;
}

// ---------------------------------------------------------------- head
// h [32,64,8,8] -> global mean -> fc (10,64) -> BN over batch -> out [32,10]
__global__ void head_kernel(const float* __restrict__ h, const float* __restrict__ fcw,
                            float* __restrict__ out) {
  __shared__ float pooled[32 * 64];
  __shared__ float logits[32 * 10];
  __shared__ float mn[10], rs[10];
  int t = threadIdx.x;
  for (int i = t; i < 32 * 64; i += blockDim.x) {
    const float* p = h + i * 64;
    float s = 0.f;
    #pragma unroll
    for (int j = 0; j < 64; j++) s += p[j];
    pooled[i] = s * (1.f / 64.f);
  }
  __syncthreads();
  for (int i = t; i < 320; i += blockDim.x) {
    int b = i / 10, o = i % 10;
    float s = 0.f;
    #pragma unroll
    for (int c = 0; c < 64; c++) s += pooled[b * 64 + c] * fcw[o * 64 + c];
    logits[i] = s;
  }
  __syncthreads();
  if (t < 10) {
    float s = 0.f;
    for (int b = 0; b < 32; b++) s += logits[b * 10 + t];
    float m = s / 32.f;
    float v = 0.f;
    for (int b = 0; b < 32; b++) { float d = logits[b * 10 + t] - m; v += d * d; }
    mn[t] = m;
    rs[t] = rsqrtf(v / 32.f + BN_EPS);
  }
  __syncthreads();
  for (int i = t; i < 320; i += blockDim.x) {
    int o = i % 10;
    out[i] = (logits[i] - mn[o]) * rs[o];
  }
}

// ---------------------------------------------------------------- host
extern "C" void kernel_launch(void* const* d_in, const int* in_sizes, int n_in,
                              void* d_out, int out_size, void* d_ws, size_t ws_size,
                              hipStream_t stream) {
  const float* x      = (const float*)d_in[0];
  const float* conv1w = (const float*)d_in[1];
  const float* l1w    = (const float*)d_in[2];
  const float* l2w0   = (const float*)d_in[3];
  const float* l2ws   = (const float*)d_in[4];
  const float* l2down = (const float*)d_in[5];
  const float* l3w0   = (const float*)d_in[6];
  const float* l3ws   = (const float*)d_in[7];
  const float* l3down = (const float*)d_in[8];
  const float* fcw    = (const float*)d_in[9];
  float* out = (float*)d_out;

  const int BUF = 32 * 16 * 32 * 32;  // 524288 floats = 2 MB, max tensor size
  float* base = (float*)d_ws;
  float* H0 = base + 0 * BUF;
  float* H1 = base + 1 * BUF;
  float* T1 = base + 2 * BUF;
  float* T2 = base + 3 * BUF;
  float* T3 = base + 4 * BUF;
  float* T4 = base + 5 * BUF;
  float* statsA = base + 6 * BUF;
  float* statsB = statsA + 128;

  const int B = 32;
  auto cdiv = [](int a, int b) { return (a + b - 1) / b; };

  // ---- stem: conv -> bn -> relu
  {
    int total = 32 * 16 * 32 * 32;
    conv_stem<<<cdiv(total, 256), 256, 0, stream>>>(x, conv1w, T1);
    bn_stats<<<16, 256, 0, stream>>>(T1, statsA, B, 16, 32 * 32);
    bn_apply<1><<<cdiv(total, 256), 256, 0, stream>>>(T1, statsA, nullptr, H0, 16, 32 * 32, total);
  }
  float* cur = H0;
  float* nxt = H1;

  auto run_block = [&](int Cin, int Cout, int H, int W, int stride,
                       const float* w1, const float* w2, const float* dw) {
    int Ho = (H + 2 - 3) / stride + 1;  // K=3 pad=1
    int Wo = Ho;
    int HWo = Ho * Wo;
    int total = B * Cout * HWo;
    // out1 = relu(bn(adder(x, w1)))
    adder2d_k<3><<<cdiv(total, 256), 256, 0, stream>>>(cur, w1, T1, B, Cin, Cout, H, W, Ho, Wo, stride, 1, total);
    bn_stats<<<Cout, 256, 0, stream>>>(T1, statsA, B, Cout, HWo);
    bn_apply<1><<<cdiv(total, 256), 256, 0, stream>>>(T1, statsA, nullptr, T2, Cout, HWo, total);
    // raw2 = adder(out1, w2); stats
    adder2d_k<3><<<cdiv(total, 256), 256, 0, stream>>>(T2, w2, T1, B, Cout, Cout, Ho, Wo, Ho, Wo, 1, 1, total);
    bn_stats<<<Cout, 256, 0, stream>>>(T1, statsA, B, Cout, HWo);
    // identity
    const float* resid = cur;
    if (dw) {
      adder2d_k<1><<<cdiv(total, 256), 256, 0, stream>>>(cur, dw, T3, B, Cin, Cout, H, W, Ho, Wo, stride, 0, total);
      bn_stats<<<Cout, 256, 0, stream>>>(T3, statsB, B, Cout, HWo);
      bn_apply<0><<<cdiv(total, 256), 256, 0, stream>>>(T3, statsB, nullptr, T4, Cout, HWo, total);
      resid = T4;
    }
    // h = relu(bn(raw2) + identity)
    bn_apply<2><<<cdiv(total, 256), 256, 0, stream>>>(T1, statsA, resid, nxt, Cout, HWo, total);
    float* tmp = cur; cur = nxt; nxt = tmp;
  };

  // ---- layer1: 3 blocks, 16ch, 32x32, stride 1
  for (int i = 0; i < 3; i++)
    run_block(16, 16, 32, 32, 1,
              l1w + (2 * i) * 16 * 16 * 9,
              l1w + (2 * i + 1) * 16 * 16 * 9, nullptr);

  // ---- layer2: 32ch, first block stride 2 + 1x1 adder downsample
  run_block(16, 32, 32, 32, 2, l2w0, l2ws + 0 * 9216, l2down);
  run_block(32, 32, 16, 16, 1, l2ws + 1 * 9216, l2ws + 2 * 9216, nullptr);
  run_block(32, 32, 16, 16, 1, l2ws + 3 * 9216, l2ws + 4 * 9216, nullptr);

  // ---- layer3: 64ch
  run_block(32, 64, 16, 16, 2, l3w0, l3ws + 0 * 36864, l3down);
  run_block(64, 64, 8, 8, 1, l3ws + 1 * 36864, l3ws + 2 * 36864, nullptr);
  run_block(64, 64, 8, 8, 1, l3ws + 3 * 36864, l3ws + 4 * 36864, nullptr);

  // ---- head
  head_kernel<<<1, 512, 0, stream>>>(cur, fcw, out);
}

// Round 2
// 526.902 us; speedup vs baseline: 2.1845x; 2.1845x over previous
//
#include <hip/hip_runtime.h>

#define BN_EPS 1e-5f

// ---------------------------------------------------------------- block reduce (scalar)
__device__ __forceinline__ float block_sum(float v) {
  __shared__ float red[9];
  int lane = threadIdx.x & 63;
  int wid  = threadIdx.x >> 6;
  #pragma unroll
  for (int off = 32; off; off >>= 1) v += __shfl_down(v, off, 64);
  __syncthreads();
  if (lane == 0) red[wid] = v;
  __syncthreads();
  if (threadIdx.x == 0) {
    float s = 0.f;
    int nw = (blockDim.x + 63) >> 6;
    for (int i = 0; i < nw; i++) s += red[i];
    red[8] = s;
  }
  __syncthreads();
  return red[8];
}

// ---------------------------------------------------------------- conv stem
// x [32,3,32,32], w [16,3,3,3], out [32,16,32,32], pad=1 stride=1 (SAME)
__global__ void conv_stem(const float* __restrict__ x, const float* __restrict__ w,
                          float* __restrict__ out) {
  int idx = blockIdx.x * blockDim.x + threadIdx.x;
  if (idx >= 32 * 16 * 32 * 32) return;
  int wo = idx & 31, ho = (idx >> 5) & 31, co = (idx >> 10) & 15, b = idx >> 14;
  float acc = 0.f;
  #pragma unroll
  for (int ci = 0; ci < 3; ci++) {
    #pragma unroll
    for (int kh = 0; kh < 3; kh++) {
      int hh = ho + kh - 1;
      #pragma unroll
      for (int kw = 0; kw < 3; kw++) {
        int ww = wo + kw - 1;
        float xv = (hh >= 0 && hh < 32 && ww >= 0 && ww < 32)
                 ? x[((b * 3 + ci) * 32 + hh) * 32 + ww] : 0.f;
        acc += xv * w[((co * 3 + ci) * 3 + kh) * 3 + kw];
      }
    }
  }
  out[idx] = acc;
}

// ---------------------------------------------------------------- adder2d + fused BN partial stats
// grid = (nChunks, Cout), block = 256. Each block: one output channel co,
// 256 consecutive elements of the flattened (b, ho, wo) space.
// out[b,co,ho,wo] = -sum_{ci,kh,kw} |x[b,ci,ho*s+kh-pad, wo*s+kw-pad] - w[co,ci,kh,kw]|
// OOB x is 0 (zero-padded patch) and STILL contributes |0-w|.
// Emits per-block (sum, sumsq) partial at partials[co*nChunks + chunk].
// REQUIRES B*Ho*Wo % 256 == 0 (true for all shapes in this net).
template<int K>
__global__ void __launch_bounds__(256)
adder_bn(const float* __restrict__ x, const float* __restrict__ w,
         float* __restrict__ out, float2* __restrict__ partials,
         int B, int Cin, int Cout, int H, int W,
         int Ho, int Wo, int stride, int pad, int nChunks) {
  __shared__ float wsm[576];                 // up to Cin=64, K=3
  __shared__ float2 red[4];
  int co = blockIdx.y;
  int chunk = blockIdx.x;
  int nW = Cin * K * K;
  for (int j = threadIdx.x; j < nW; j += 256) wsm[j] = w[co * nW + j];
  __syncthreads();

  int i = chunk * 256 + threadIdx.x;         // index into (b, ho, wo)
  int HWo = Ho * Wo;
  int b = i / HWo;
  int hw = i - b * HWo;
  int ho = hw / Wo, wo = hw - ho * Wo;

  float acc = 0.f;
  for (int ci = 0; ci < Cin; ci++) {
    const float* xp = x + (b * Cin + ci) * H * W;
    const float* wp = wsm + ci * K * K;
    #pragma unroll
    for (int kh = 0; kh < K; kh++) {
      int hh = ho * stride + kh - pad;
      bool hv = (hh >= 0) && (hh < H);
      #pragma unroll
      for (int kw = 0; kw < K; kw++) {
        int ww = wo * stride + kw - pad;
        float xv = (hv && ww >= 0 && ww < W) ? xp[hh * W + ww] : 0.f;
        acc += fabsf(xv - wp[kh * K + kw]);
      }
    }
  }
  float v = -acc;
  out[(b * Cout + co) * HWo + hw] = v;

  // block reduce (v, v*v)
  float sx = v, sy = v * v;
  #pragma unroll
  for (int off = 32; off; off >>= 1) {
    sx += __shfl_down(sx, off, 64);
    sy += __shfl_down(sy, off, 64);
  }
  int lane = threadIdx.x & 63, wid = threadIdx.x >> 6;
  if (lane == 0) red[wid] = make_float2(sx, sy);
  __syncthreads();
  if (threadIdx.x == 0) {
    float2 t = red[0];
    t.x += red[1].x + red[2].x + red[3].x;
    t.y += red[1].y + red[2].y + red[3].y;
    partials[co * nChunks + chunk] = t;
  }
}

// ---------------------------------------------------------------- generic BN partial (for stem)
// grid = (chunksPerC, C), block 256. Tensor layout [B, C, HW].
__global__ void bn_partial(const float* __restrict__ xt, float2* __restrict__ partials,
                           int C, int HW, int chunksPerC) {
  int c = blockIdx.y;
  int j = blockIdx.x * 256 + threadIdx.x;    // index into (b, pos)
  int b = j / HW;
  int pos = j - b * HW;
  float v = xt[(b * C + c) * HW + pos];
  float sx = v, sy = v * v;
  #pragma unroll
  for (int off = 32; off; off >>= 1) {
    sx += __shfl_down(sx, off, 64);
    sy += __shfl_down(sy, off, 64);
  }
  __shared__ float2 red[4];
  int lane = threadIdx.x & 63, wid = threadIdx.x >> 6;
  if (lane == 0) red[wid] = make_float2(sx, sy);
  __syncthreads();
  if (threadIdx.x == 0) {
    float2 t = red[0];
    t.x += red[1].x + red[2].x + red[3].x;
    t.y += red[1].y + red[2].y + red[3].y;
    partials[c * chunksPerC + blockIdx.x] = t;
  }
}

// ---------------------------------------------------------------- BN finalize
// grid = C blocks, 64 threads (one wave). stats: [mean[C], rstd[C]]
__global__ void bn_finalize(const float2* __restrict__ partials, float* __restrict__ stats,
                            int C, int S, float invN) {
  int c = blockIdx.x;
  float s = 0.f, s2 = 0.f;
  for (int j = threadIdx.x; j < S; j += 64) {
    float2 p = partials[c * S + j];
    s += p.x; s2 += p.y;
  }
  #pragma unroll
  for (int off = 32; off; off >>= 1) {
    s  += __shfl_down(s, off, 64);
    s2 += __shfl_down(s2, off, 64);
  }
  if (threadIdx.x == 0) {
    float m = s * invN;
    float var = fmaxf(s2 * invN - m * m, 0.f);
    stats[c]     = m;
    stats[C + c] = rsqrtf(var + BN_EPS);
  }
}

// ---------------------------------------------------------------- BN apply
// MODE 0: bn   MODE 1: bn+relu   MODE 2: bn + residual + relu
template<int MODE>
__global__ void bn_apply(const float* __restrict__ x, const float* __restrict__ stats,
                         const float* __restrict__ res, float* __restrict__ out,
                         int C, int HW, int total) {
  int idx = blockIdx.x * blockDim.x + threadIdx.x;
  if (idx >= total) return;
  int c = (idx / HW) % C;
  float y = (x[idx] - stats[c]) * stats[C + c];
  if (MODE == 1) y = fmaxf(y, 0.f);
  if (MODE == 2) { y += res[idx]; y = fmaxf(y, 0.f); }
  out[idx] = y;
}

// ---------------------------------------------------------------- head
// h [32,64,8,8] -> global mean -> fc (10,64) -> BN over batch -> out [32,10]
__global__ void head_kernel(const float* __restrict__ h, const float* __restrict__ fcw,
                            float* __restrict__ out) {
  __shared__ float pooled[32 * 64];
  __shared__ float logits[32 * 10];
  __shared__ float mn[10], rs[10];
  int t = threadIdx.x;
  for (int i = t; i < 32 * 64; i += blockDim.x) {
    const float* p = h + i * 64;
    float s = 0.f;
    #pragma unroll
    for (int j = 0; j < 64; j++) s += p[j];
    pooled[i] = s * (1.f / 64.f);
  }
  __syncthreads();
  for (int i = t; i < 320; i += blockDim.x) {
    int b = i / 10, o = i % 10;
    float s = 0.f;
    #pragma unroll
    for (int c = 0; c < 64; c++) s += pooled[b * 64 + c] * fcw[o * 64 + c];
    logits[i] = s;
  }
  __syncthreads();
  if (t < 10) {
    float s = 0.f;
    for (int b = 0; b < 32; b++) s += logits[b * 10 + t];
    float m = s / 32.f;
    float v = 0.f;
    for (int b = 0; b < 32; b++) { float d = logits[b * 10 + t] - m; v += d * d; }
    mn[t] = m;
    rs[t] = rsqrtf(v / 32.f + BN_EPS);
  }
  __syncthreads();
  for (int i = t; i < 320; i += blockDim.x) {
    int o = i % 10;
    out[i] = (logits[i] - mn[o]) * rs[o];
  }
}

// ---------------------------------------------------------------- host
extern "C" void kernel_launch(void* const* d_in, const int* in_sizes, int n_in,
                              void* d_out, int out_size, void* d_ws, size_t ws_size,
                              hipStream_t stream) {
  const float* x      = (const float*)d_in[0];
  const float* conv1w = (const float*)d_in[1];
  const float* l1w    = (const float*)d_in[2];
  const float* l2w0   = (const float*)d_in[3];
  const float* l2ws   = (const float*)d_in[4];
  const float* l2down = (const float*)d_in[5];
  const float* l3w0   = (const float*)d_in[6];
  const float* l3ws   = (const float*)d_in[7];
  const float* l3down = (const float*)d_in[8];
  const float* fcw    = (const float*)d_in[9];
  float* out = (float*)d_out;

  const int BUF = 32 * 16 * 32 * 32;  // 524288 floats = 2 MB, max tensor size
  float* base = (float*)d_ws;
  float* H0 = base + 0 * BUF;
  float* H1 = base + 1 * BUF;
  float* T1 = base + 2 * BUF;
  float* T2 = base + 3 * BUF;
  float* T3 = base + 4 * BUF;
  float* T4 = base + 5 * BUF;
  float* statsA = base + 6 * BUF;        // 128 floats
  float* statsB = statsA + 128;          // 128 floats
  float2* partA = (float2*)(statsB + 128);          // up to 2048 float2
  float2* partB = partA + 2048;

  const int B = 32;
  auto cdiv = [](int a, int b) { return (a + b - 1) / b; };

  // ---- stem: conv -> bn -> relu
  {
    int total = 32 * 16 * 32 * 32;
    conv_stem<<<cdiv(total, 256), 256, 0, stream>>>(x, conv1w, T1);
    int chunksPerC = (32 * 1024) / 256;   // 128
    bn_partial<<<dim3(chunksPerC, 16), 256, 0, stream>>>(T1, partA, 16, 1024, chunksPerC);
    bn_finalize<<<16, 64, 0, stream>>>(partA, statsA, 16, chunksPerC, 1.f / (32.f * 1024.f));
    bn_apply<1><<<cdiv(total, 256), 256, 0, stream>>>(T1, statsA, nullptr, H0, 16, 1024, total);
  }
  float* cur = H0;
  float* nxt = H1;

  auto run_block = [&](int Cin, int Cout, int H, int W, int stride,
                       const float* w1, const float* w2, const float* dw) {
    int Ho = (H + 2 - 3) / stride + 1;  // K=3 pad=1
    int Wo = Ho;
    int HWo = Ho * Wo;
    int N = B * HWo;                    // spatial*batch total, % 256 == 0
    int nChunks = N / 256;
    int total = B * Cout * HWo;
    float invN = 1.f / (float)N;
    // out1 = relu(bn(adder(x, w1)))
    adder_bn<3><<<dim3(nChunks, Cout), 256, 0, stream>>>(cur, w1, T1, partA, B, Cin, Cout, H, W, Ho, Wo, stride, 1, nChunks);
    bn_finalize<<<Cout, 64, 0, stream>>>(partA, statsA, Cout, nChunks, invN);
    bn_apply<1><<<cdiv(total, 256), 256, 0, stream>>>(T1, statsA, nullptr, T2, Cout, HWo, total);
    // raw2 = adder(out1, w2) + stats
    adder_bn<3><<<dim3(nChunks, Cout), 256, 0, stream>>>(T2, w2, T1, partA, B, Cout, Cout, Ho, Wo, Ho, Wo, 1, 1, nChunks);
    bn_finalize<<<Cout, 64, 0, stream>>>(partA, statsA, Cout, nChunks, invN);
    // identity
    const float* resid = cur;
    if (dw) {
      adder_bn<1><<<dim3(nChunks, Cout), 256, 0, stream>>>(cur, dw, T3, partB, B, Cin, Cout, H, W, Ho, Wo, stride, 0, nChunks);
      bn_finalize<<<Cout, 64, 0, stream>>>(partB, statsB, Cout, nChunks, invN);
      bn_apply<0><<<cdiv(total, 256), 256, 0, stream>>>(T3, statsB, nullptr, T4, Cout, HWo, total);
      resid = T4;
    }
    // h = relu(bn(raw2) + identity)
    bn_apply<2><<<cdiv(total, 256), 256, 0, stream>>>(T1, statsA, resid, nxt, Cout, HWo, total);
    float* tmp = cur; cur = nxt; nxt = tmp;
  };

  // ---- layer1: 3 blocks, 16ch, 32x32, stride 1
  for (int i = 0; i < 3; i++)
    run_block(16, 16, 32, 32, 1,
              l1w + (2 * i) * 16 * 16 * 9,
              l1w + (2 * i + 1) * 16 * 16 * 9, nullptr);

  // ---- layer2: 32ch, first block stride 2 + 1x1 adder downsample
  run_block(16, 32, 32, 32, 2, l2w0, l2ws + 0 * 9216, l2down);
  run_block(32, 32, 16, 16, 1, l2ws + 1 * 9216, l2ws + 2 * 9216, nullptr);
  run_block(32, 32, 16, 16, 1, l2ws + 3 * 9216, l2ws + 4 * 9216, nullptr);

  // ---- layer3: 64ch
  run_block(32, 64, 16, 16, 2, l3w0, l3ws + 0 * 36864, l3down);
  run_block(64, 64, 8, 8, 1, l3ws + 1 * 36864, l3ws + 2 * 36864, nullptr);
  run_block(64, 64, 8, 8, 1, l3ws + 3 * 36864, l3ws + 4 * 36864, nullptr);

  // ---- head
  head_kernel<<<1, 512, 0, stream>>>(cur, fcw, out);
}